// Round 9
// baseline (1459.065 us; speedup 1.0000x reference)
//
#include <hip/hip_runtime.h>
#include <hip/hip_bf16.h>
#include <math.h>

#define BB 4
#define TT 2048
#define VV 99
#define DD 512
#define HH 8
#define LL 6
#define DHH 64
#define OFFS 28
#define ROWS (BB*TT)   // 8192

typedef __hip_bfloat16 bf16;
typedef __attribute__((ext_vector_type(8))) short bf16x8;
typedef __attribute__((ext_vector_type(4))) short s16x4;
typedef __attribute__((ext_vector_type(4))) float f32x4;

__device__ __forceinline__ float b2f(bf16 x){ return __bfloat162float(x); }

// async 16B/lane global->LDS. LDS dest = wave-uniform base + lane*16 (m97 pattern).
__device__ __forceinline__ void async_copy16(const void* g, void* l){
    __builtin_amdgcn_global_load_lds(
        (const __attribute__((address_space(1))) unsigned int*)g,
        (__attribute__((address_space(3))) unsigned int*)l, 16, 0, 0);
}

// 32-bit LDS byte offset for DS inline asm (generic -> AS3 cast)
__device__ __forceinline__ unsigned lds_off(const void* p){
    return (unsigned)(size_t)(const __attribute__((address_space(3))) char*)p;
}

// ds_read_b64_tr_b16 cooperative 16-lane transpose; per-lane addr = base + 8*lane.
#define TRD(dst, a, lit) asm volatile("ds_read_b64_tr_b16 %0, %1 offset:" lit \
                                      : "=v"(dst) : "v"(a) : "memory")
#define CAT8(lo, hi) ((bf16x8)__builtin_shufflevector((lo), (hi), 0,1,2,3,4,5,6,7))

__device__ __forceinline__ unsigned pk2(float a, float b){
    return ((unsigned)(unsigned short)__bfloat16_as_short(__float2bfloat16(a)))
         | ((unsigned)(unsigned short)__bfloat16_as_short(__float2bfloat16(b)) << 16);
}

// T1: bijective XCD-aware block remap (requires nwg%8==0; all our grids satisfy).
__device__ __forceinline__ void xcd_swz(int gx, int gy, int &bx, int &by){
    int nwg = gx * gy;
    int orig = by * gx + bx;
    int q = nwg >> 3;
    int nid = (orig & 7) * q + (orig >> 3);
    bx = nid % gx;
    by = nid / gx;
}

// mode-dispatched weight read from a raw base + element offset (mode1 = bf16 inputs)
__device__ __forceinline__ float wget(const void* w, int mode, size_t i){
    return mode ? b2f(((const bf16*)w)[i]) : ((const float*)w)[i];
}

// ---------------- init ----------------
__global__ void init_kernel(const unsigned int* __restrict__ ln1_bits, float* __restrict__ acc,
                            int* __restrict__ flag){
    acc[0] = 0.f; acc[1] = 0.f;
    flag[0] = (ln1_bits[0] == 0x3F800000u) ? 0 : 1;
}

// ---------------- weight convert: any-dtype -> bf16, 8 elems/thread ----------------
__global__ __launch_bounds__(256) void wconv_kernel(const void* __restrict__ src,
                                                    bf16* __restrict__ dst, int n,
                                                    const int* __restrict__ flag){
    int mode = flag[0];
    size_t i0 = ((size_t)blockIdx.x*256 + threadIdx.x)*8;
    if (i0 >= (size_t)n) return;
    if (mode == 0){
        const float4* sp = (const float4*)((const float*)src + i0);
        float4 a = sp[0], b = sp[1];
        float f[8] = {a.x,a.y,a.z,a.w, b.x,b.y,b.z,b.w};
        union { short s[8]; uint4 u; } cv;
        #pragma unroll
        for (int k=0;k<8;++k) cv.s[k] = __bfloat16_as_short(__float2bfloat16(f[k]));
        *(uint4*)(dst + i0) = cv.u;
    } else {
        *(uint4*)(dst + i0) = *(const uint4*)((const bf16*)src + i0);
    }
}

// ---------------- embedding: X in bf16 ----------------
__global__ void embed_kernel(const int* __restrict__ idx, const void* __restrict__ wte,
                             const void* __restrict__ wpe, bf16* __restrict__ x,
                             const int* __restrict__ flag){
    int mode = flag[0];
    int row = blockIdx.x;
    int t = row % TT;
    int tok = idx[row];
    int i = threadIdx.x;
    #pragma unroll
    for (int j = 0; j < 2; ++j){
        int d = i + j*256;
        x[(size_t)row*DD + d] = __float2bfloat16(
              wget(wte, mode, (size_t)tok*DD + d)
            + wget(wpe, mode, (size_t)t*DD + d));
    }
}

// ---------------- layernorm: bf16 X in (vectorized bf16x8), bf16 out ----------------
// Lane owns cols [lane*8, lane*8+8): one 16B contiguous load/store per lane.
__global__ void ln_kernel(const bf16* __restrict__ x, const void* __restrict__ w,
                          size_t woff, bf16* __restrict__ out, const int* __restrict__ flag){
    int mode = flag[0];
    int row = blockIdx.x;
    int lane = threadIdx.x; // 64
    const bf16* xr = x + (size_t)row*DD + lane*8;
    bf16x8 xv = *(const bf16x8*)xr;
    float v[8];
    float s = 0.f;
    #pragma unroll
    for (int j=0;j<8;++j){
        union { short s16; unsigned short u; } cu; cu.s16 = xv[j];
        union { unsigned short u; } dummy; (void)dummy;
        bf16 bb = __ushort_as_bfloat16(cu.u);
        v[j] = __bfloat162float(bb);
        s += v[j];
    }
    #pragma unroll
    for (int o=32;o;o>>=1) s += __shfl_xor(s,o);
    float mean = s * (1.0f/DD);
    float vs = 0.f;
    #pragma unroll
    for (int j=0;j<8;++j){ float d = v[j]-mean; vs += d*d; }
    #pragma unroll
    for (int o=32;o;o>>=1) vs += __shfl_xor(vs,o);
    float rstd = rsqrtf(vs*(1.0f/DD) + 1e-5f);
    union { short s16[8]; bf16x8 v8; } ov;
    #pragma unroll
    for (int j=0;j<8;++j){
        int d = lane*8 + j;
        ov.s16[j] = __bfloat16_as_short(__float2bfloat16((v[j]-mean)*rstd*wget(w,mode,woff+d)));
    }
    *(bf16x8*)(out + (size_t)row*DD + lane*8) = ov.v8;
}

// ---------------- MFMA GEMM 128x128, BK=64 (half the barrier events vs BK=32) ----------------
// C[M,N] = A[M,K] @ W[N,K]^T. XOR chunk swizzle on LDS rows (pre-swizzled global src,
// rule #21): row j slot s holds content chunk s^(j&7) -> conflict-spread ds_read_b128.
// EPI: 0 = bf16 store Cb, 2 = gelu -> bf16 Cb. T1 XCD swizzle kept.
template<int EPI>
__global__ __launch_bounds__(256) void gemm_mfma(const bf16* __restrict__ A,
        const bf16* __restrict__ W, float* __restrict__ C, bf16* __restrict__ Cb,
        int M, int N, int K){
    __shared__ short As[128*64];
    __shared__ short Ws[128*64];
    int tid = threadIdx.x;
    int bx = blockIdx.x, by = blockIdx.y;
    xcd_swz((int)gridDim.x, (int)gridDim.y, bx, by);
    int m0 = by * 128;
    int n0 = bx * 128;
    int lane = tid & 63, wave = tid >> 6;
    int wm = (wave & 1) * 64, wn = (wave >> 1) * 64;
    int quad = lane >> 4, l16 = lane & 15;

    f32x4 acc[4][4] = {};

    // staging: wave w rows w*32..w*32+31, 4 copies of 8 rows each.
    // lane l: row = w*32 + i*8 + (l>>3), slot = l&7, content chunk = (l&7)^((l>>3)&7)
    int srow = wave*32 + (lane >> 3);
    int scol = ((lane&7) ^ ((lane>>3)&7)) * 8;
    const bf16* ga = A + (size_t)(m0 + srow)*K + scol;
    const bf16* gw = W + (size_t)(n0 + srow)*K + scol;
    short* dA = &As[(wave*32)*64];
    short* dW = &Ws[(wave*32)*64];

    for (int k0 = 0; k0 < K; k0 += 64){
        __syncthreads();
        async_copy16(ga + k0,                  dA);
        async_copy16(ga + (size_t)8*K  + k0,   dA + 8*64);
        async_copy16(ga + (size_t)16*K + k0,   dA + 16*64);
        async_copy16(ga + (size_t)24*K + k0,   dA + 24*64);
        async_copy16(gw + k0,                  dW);
        async_copy16(gw + (size_t)8*K  + k0,   dW + 8*64);
        async_copy16(gw + (size_t)16*K + k0,   dW + 16*64);
        async_copy16(gw + (size_t)24*K + k0,   dW + 24*64);
        __syncthreads();

        int sw = l16 & 7;
        #pragma unroll
        for (int s = 0; s < 2; ++s){
            bf16x8 af[4], bfr[4];
            #pragma unroll
            for (int mi=0;mi<4;++mi){
                int r = wm + mi*16 + l16;
                af[mi] = *(const bf16x8*)&As[r*64 + ((((s<<2)|quad) ^ sw)<<3)];
            }
            #pragma unroll
            for (int ni=0;ni<4;++ni){
                int r = wn + ni*16 + l16;
                bfr[ni] = *(const bf16x8*)&Ws[r*64 + ((((s<<2)|quad) ^ sw)<<3)];
            }
            #pragma unroll
            for (int mi=0;mi<4;++mi)
                #pragma unroll
                for (int ni=0;ni<4;++ni)
                    acc[mi][ni] = __builtin_amdgcn_mfma_f32_16x16x32_bf16(af[mi], bfr[ni], acc[mi][ni], 0, 0, 0);
        }
    }

    #pragma unroll
    for (int mi=0;mi<4;++mi){
        #pragma unroll
        for (int ni=0;ni<4;++ni){
            int mg = m0 + wm + mi*16 + quad*4;
            int ng = n0 + wn + ni*16 + l16;
            #pragma unroll
            for (int reg=0;reg<4;++reg){
                float val = acc[mi][ni][reg];
                size_t off = (size_t)(mg+reg)*N + ng;
                if (EPI==0){
                    Cb[off] = __float2bfloat16(val);
                } else {
                    float xx = val;
                    float u = 0.7978845608028654f*(xx + 0.044715f*xx*xx*xx);
                    Cb[off] = __float2bfloat16(0.5f*xx*(1.0f+tanhf(u)));
                }
            }
        }
    }
}

// ---------------- MFMA GEMM 64x128, BK=64, swizzled; bf16 += residual ----------------
__global__ __launch_bounds__(256) void gemm_mfma64(const bf16* __restrict__ A,
        const bf16* __restrict__ W, bf16* __restrict__ C, int M, int N, int K){
    __shared__ short As[64*64];
    __shared__ short Ws[128*64];
    int tid = threadIdx.x;
    int bx = blockIdx.x, by = blockIdx.y;
    xcd_swz((int)gridDim.x, (int)gridDim.y, bx, by);
    int m0 = by * 64;
    int n0 = bx * 128;
    int lane = tid & 63, wave = tid >> 6;
    int wm = (wave & 1) * 32, wn = (wave >> 1) * 64;
    int quad = lane >> 4, l16 = lane & 15;

    f32x4 acc[2][4] = {};

    int scol = ((lane&7) ^ ((lane>>3)&7)) * 8;
    int srowA = wave*16 + (lane >> 3);   // A: wave w rows w*16..+15 (2 copies)
    int srowW = wave*32 + (lane >> 3);   // W: wave w rows w*32..+31 (4 copies)
    const bf16* ga = A + (size_t)(m0 + srowA)*K + scol;
    const bf16* gw = W + (size_t)(n0 + srowW)*K + scol;
    short* dA = &As[(wave*16)*64];
    short* dW = &Ws[(wave*32)*64];

    for (int k0 = 0; k0 < K; k0 += 64){
        __syncthreads();
        async_copy16(ga + k0,                  dA);
        async_copy16(ga + (size_t)8*K  + k0,   dA + 8*64);
        async_copy16(gw + k0,                  dW);
        async_copy16(gw + (size_t)8*K  + k0,   dW + 8*64);
        async_copy16(gw + (size_t)16*K + k0,   dW + 16*64);
        async_copy16(gw + (size_t)24*K + k0,   dW + 24*64);
        __syncthreads();

        int sw = l16 & 7;
        #pragma unroll
        for (int s = 0; s < 2; ++s){
            bf16x8 af[2], bfr[4];
            #pragma unroll
            for (int mi=0;mi<2;++mi){
                int r = wm + mi*16 + l16;
                af[mi] = *(const bf16x8*)&As[r*64 + ((((s<<2)|quad) ^ sw)<<3)];
            }
            #pragma unroll
            for (int ni=0;ni<4;++ni){
                int r = wn + ni*16 + l16;
                bfr[ni] = *(const bf16x8*)&Ws[r*64 + ((((s<<2)|quad) ^ sw)<<3)];
            }
            #pragma unroll
            for (int mi=0;mi<2;++mi)
                #pragma unroll
                for (int ni=0;ni<4;++ni)
                    acc[mi][ni] = __builtin_amdgcn_mfma_f32_16x16x32_bf16(af[mi], bfr[ni], acc[mi][ni], 0, 0, 0);
        }
    }

    #pragma unroll
    for (int mi=0;mi<2;++mi){
        #pragma unroll
        for (int ni=0;ni<4;++ni){
            int mg = m0 + wm + mi*16 + quad*4;
            int ng = n0 + wn + ni*16 + l16;
            #pragma unroll
            for (int reg=0;reg<4;++reg){
                size_t off = (size_t)(mg+reg)*N + ng;
                C[off] = __float2bfloat16(__bfloat162float(C[off]) + acc[mi][ni][reg]);
            }
        }
    }
}

// ---------------- VALU GEMM (logits: N=99), fp32 store ----------------
__global__ __launch_bounds__(256) void gemm_nt3(const bf16* __restrict__ A,
        const void* __restrict__ W, size_t woff, float* __restrict__ C,
        int M, int N, int K, const int* __restrict__ flag){
    int mode = flag[0];
    __shared__ float As[16][64];
    __shared__ float Wt[16][64];
    int m0 = blockIdx.y * 64;
    int n0 = blockIdx.x * 64;
    int t = threadIdx.x;
    int tx = t & 15, ty = t >> 4;
    float acc[4][4] = {};
    int am = t >> 2;
    int ak = (t & 3) * 4;

    for (int k0 = 0; k0 < K; k0 += 16){
        {
            const __hip_bfloat162* ap = (const __hip_bfloat162*)(A + (size_t)(m0+am)*K + k0 + ak);
            __hip_bfloat162 p0 = ap[0], p1 = ap[1];
            float2 f0 = __bfloat1622float2(p0), f1 = __bfloat1622float2(p1);
            As[ak+0][am]=f0.x; As[ak+1][am]=f0.y; As[ak+2][am]=f1.x; As[ak+3][am]=f1.y;
        }
        int wn = n0 + am;
        if (wn < N){
            size_t off = woff + (size_t)wn*K + k0 + ak;
            if (mode == 0){
                float4 wv = *(const float4*)((const float*)W + off);
                Wt[ak+0][am]=wv.x; Wt[ak+1][am]=wv.y; Wt[ak+2][am]=wv.z; Wt[ak+3][am]=wv.w;
            } else {
                const __hip_bfloat162* wp = (const __hip_bfloat162*)((const bf16*)W + off);
                __hip_bfloat162 p0 = wp[0], p1 = wp[1];
                float2 f0 = __bfloat1622float2(p0), f1 = __bfloat1622float2(p1);
                Wt[ak+0][am]=f0.x; Wt[ak+1][am]=f0.y; Wt[ak+2][am]=f1.x; Wt[ak+3][am]=f1.y;
            }
        } else {
            Wt[ak+0][am]=0.f; Wt[ak+1][am]=0.f; Wt[ak+2][am]=0.f; Wt[ak+3][am]=0.f;
        }
        __syncthreads();
        #pragma unroll
        for (int kk=0;kk<16;++kk){
            float a[4], b[4];
            #pragma unroll
            for (int i=0;i<4;++i) a[i]=As[kk][ty*4+i];
            #pragma unroll
            for (int j=0;j<4;++j) b[j]=Wt[kk][tx*4+j];
            #pragma unroll
            for (int i=0;i<4;++i)
                #pragma unroll
                for (int j=0;j<4;++j)
                    acc[i][j] += a[i]*b[j];
        }
        __syncthreads();
    }

    #pragma unroll
    for (int i=0;i<4;++i){
        int m = m0 + ty*4 + i;
        #pragma unroll
        for (int j=0;j<4;++j){
            int n = n0 + tx*4 + j;
            if (n >= N) continue;
            C[(size_t)m*N+n] = acc[i][j];
        }
    }
}

// ---------------- attention v11 (R5/R7-proven, exact revert of the Q-fold) ----------------
__global__ __launch_bounds__(256) void attn_mfma11(const bf16* __restrict__ qkv,
                                                   bf16* __restrict__ y){
    __shared__ __align__(16) short Ks[4][4096];
    __shared__ __align__(16) short Vs[4][4096];
    __shared__ __align__(16) short P2[4][1024];   // per-wave [16 q][64 k]

    int tid = threadIdx.x;
    int lane = tid & 63, wave = tid >> 6;
    int quad = lane >> 4, l16 = lane & 15;

    int bi = blockIdx.x;
    int qt = 31 - (bi >> 5);       // qt-major: all big tiles first
    int bh = bi & 31;
    int h = bh & 7;
    int b = bh >> 3;
    int q0 = qt * 64;
    size_t base = (size_t)b * TT * 1536;

    // Q frags direct from global (row-major, 16B contiguous); B-operand of swapped MFMA.
    const bf16* qrow = qkv + base + (size_t)(q0 + wave*16 + l16)*1536 + h*64;
    bf16x8 aq0 = *(const bf16x8*)(qrow + quad*8);
    bf16x8 aq1 = *(const bf16x8*)(qrow + 32 + quad*8);

    // K staging source (swizzle pre-applied on global src, rule #21)
    int kj  = wave*16 + (lane>>3);
    int kgo = ((lane&7) ^ ((lane>>3)&7)) << 3;
    // V staging source (4x16-subtiled layout for tr-reads)
    int vj  = ((lane>>3)&3)*8 + ((lane>>5)&1)*4 + ((lane>>1)&3);
    int vdo = wave*16 + ((lane&1)<<3);
    const bf16* ks0 = qkv + base + DD   + h*64 + (size_t)kj*1536 + kgo;
    const bf16* vs0 = qkv + base + 2*DD + h*64 + (size_t)vj*1536 + vdo;
    short* kd = &Ks[0][0] + wave*1024;
    short* vd = &Vs[0][0] + wave*1024;

#define STAGE(bb, j0s) { \
    const bf16* kk_ = ks0 + (size_t)(j0s)*1536; \
    const bf16* vv_ = vs0 + (size_t)(j0s)*1536; \
    short* kdd_ = kd + (bb)*4096; \
    short* vdd_ = vd + (bb)*4096; \
    async_copy16(kk_,                    kdd_); \
    async_copy16(kk_ + (size_t)8*1536,   kdd_ + 512); \
    async_copy16(vv_,                    vdd_); \
    async_copy16(vv_ + (size_t)32*1536,  vdd_ + 512); }

    f32x4 O[4] = {};
    float mr1 = -1e30f;   // running max for q=l16
    float lr1 = 0.f;      // running denom for q=l16

    int jbmax = qt + 1; if (jbmax > 31) jbmax = 31;
    int NT = jbmax + 1;

    STAGE(0, 0);
    if (NT > 1) STAGE(1, 64);
    __syncthreads();

    unsigned l8 = (unsigned)(lane << 3);
    unsigned vbase = lds_off(&Vs[0][0]) + l8;
    char* pw = (char*)&P2[wave][0];
    int swz = (l16 & 7) << 4;
    int qg_row = q0 + wave*16 + l16;   // this lane's softmax row
    int sb = (quad<<4) | (quad<<2);    // broadcast source lane base

#define ATTN_BODY(tt) { \
    int t_ = (tt); \
    int j0 = t_ * 64; \
    const short* kb = &Ks[0][0] + (t_&3)*4096; \
    f32x4 s4[4]; \
    _Pragma("unroll") \
    for (int ni=0; ni<4; ++ni){ \
        int R = ni*16 + l16; \
        int ro = R*64; \
        int sw = R & 7; \
        bf16x8 bk0 = *(const bf16x8*)&kb[ro + ((quad       ^ sw)<<3)]; \
        bf16x8 bk1 = *(const bf16x8*)&kb[ro + (((quad + 4) ^ sw)<<3)]; \
        f32x4 z = {}; \
        z = __builtin_amdgcn_mfma_f32_16x16x32_bf16(bk0, aq0, z, 0, 0, 0); \
        z = __builtin_amdgcn_mfma_f32_16x16x32_bf16(bk1, aq1, z, 0, 0, 0); \
        s4[ni] = z; \
    } \
    float sc[4][4]; \
    bool bd = (j0 + 63 > q0 + OFFS); \
    _Pragma("unroll") \
    for (int ni=0; ni<4; ++ni){ \
        _Pragma("unroll") \
        for (int reg=0; reg<4; ++reg){ \
            float v = s4[ni][reg] * 0.125f; \
            if (bd){ \
                int jg = j0 + ni*16 + quad*4 + reg; \
                if (jg > qg_row + OFFS) v = -1e30f; \
            } \
            sc[ni][reg] = v; \
        } \
    } \
    float mn[4]; \
    _Pragma("unroll") \
    for (int ni=0; ni<4; ++ni) \
        mn[ni] = fmaxf(fmaxf(sc[ni][0], sc[ni][1]), fmaxf(sc[ni][2], sc[ni][3])); \
    float m16 = fmaxf(fmaxf(mn[0], mn[1]), fmaxf(mn[2], mn[3])); \
    m16 = fmaxf(m16, __shfl_xor(m16, 16)); \
    m16 = fmaxf(m16, __shfl_xor(m16, 32)); \
    float nm; \
    float alpha1 = 1.0f; \
    if (__all(m16 <= mr1 + 8.0f)){ \
        nm = mr1;            /* defer-max: keep old max, P bounded by e^8 */ \
    } else { \
        nm = fmaxf(mr1, m16); \
        alpha1 = __expf(mr1 - nm); \
        mr1 = nm; \
        float al0 = __shfl(alpha1, sb); \
        float al1 = __shfl(alpha1, sb+1); \
        float al2 = __shfl(alpha1, sb+2); \
        float al3 = __shfl(alpha1, sb+3); \
        _Pragma("unroll") \
        for (int dt=0; dt<4; ++dt){ \
            O[dt][0] *= al0; O[dt][1] *= al1; O[dt][2] *= al2; O[dt][3] *= al3; \
        } \
    } \
    float rsn[4]; \
    _Pragma("unroll") \
    for (int ni=0; ni<4; ++ni){ \
        _Pragma("unroll") \
        for (int reg=0; reg<4; ++reg) \
            sc[ni][reg] = __expf(sc[ni][reg] - nm); \
        rsn[ni] = (sc[ni][0] + sc[ni][1]) + (sc[ni][2] + sc[ni][3]); \
    } \
    float rs1 = (rsn[0] + rsn[1]) + (rsn[2] + rsn[3]); \
    rs1 += __shfl_xor(rs1, 16); \
    rs1 += __shfl_xor(rs1, 32); \
    lr1 = lr1*alpha1 + rs1; \
    __builtin_amdgcn_sched_barrier(0); \
    unsigned va = vbase + (unsigned)((t_&3)*8192); \
    s16x4 t000,t001,t010,t011, t100,t101,t110,t111, \
          t200,t201,t210,t211, t300,t301,t310,t311; \
    TRD(t000, va, "0");    TRD(t001, va, "512");  TRD(t010, va, "1024"); TRD(t011, va, "1536"); \
    TRD(t100, va, "2048"); TRD(t101, va, "2560"); TRD(t110, va, "3072"); TRD(t111, va, "3584"); \
    TRD(t200, va, "4096"); TRD(t201, va, "4608"); TRD(t210, va, "5120"); TRD(t211, va, "5632"); \
    TRD(t300, va, "6144"); TRD(t301, va, "6656"); TRD(t310, va, "7168"); TRD(t311, va, "7680"); \
    _Pragma("unroll") \
    for (int ni=0; ni<4; ++ni){ \
        unsigned lo = pk2(sc[ni][0], sc[ni][1]); \
        unsigned hi = pk2(sc[ni][2], sc[ni][3]); \
        *(uint2*)(pw + (((l16<<7) + (ni<<5) + (quad<<3)) ^ swz)) = make_uint2(lo, hi); \
    } \
    bf16x8 ap0 = *(const bf16x8*)(pw + (((l16<<7)      + (quad<<4)) ^ swz)); \
    bf16x8 ap1 = *(const bf16x8*)(pw + (((l16<<7) + 64 + (quad<<4)) ^ swz)); \
    asm volatile("s_waitcnt lgkmcnt(0)" ::: "memory"); \
    __builtin_amdgcn_sched_barrier(0); \
    O[0] = __builtin_amdgcn_mfma_f32_16x16x32_bf16(ap0, CAT8(t000,t001), O[0], 0, 0, 0); \
    O[1] = __builtin_amdgcn_mfma_f32_16x16x32_bf16(ap0, CAT8(t100,t101), O[1], 0, 0, 0); \
    O[2] = __builtin_amdgcn_mfma_f32_16x16x32_bf16(ap0, CAT8(t200,t201), O[2], 0, 0, 0); \
    O[3] = __builtin_amdgcn_mfma_f32_16x16x32_bf16(ap0, CAT8(t300,t301), O[3], 0, 0, 0); \
    O[0] = __builtin_amdgcn_mfma_f32_16x16x32_bf16(ap1, CAT8(t010,t011), O[0], 0, 0, 0); \
    O[1] = __builtin_amdgcn_mfma_f32_16x16x32_bf16(ap1, CAT8(t110,t111), O[1], 0, 0, 0); \
    O[2] = __builtin_amdgcn_mfma_f32_16x16x32_bf16(ap1, CAT8(t210,t211), O[2], 0, 0, 0); \
    O[3] = __builtin_amdgcn_mfma_f32_16x16x32_bf16(ap1, CAT8(t310,t311), O[3], 0, 0, 0); }

    for (int tp = 0; tp < NT; tp += 2){
        if (tp+2 < NT) STAGE((tp+2)&3, (tp+2)*64);
        if (tp+3 < NT) STAGE((tp+3)&3, (tp+3)*64);
        ATTN_BODY(tp);
        if (tp+1 < NT) ATTN_BODY(tp+1);
        __syncthreads();   // one barrier per PAIR: drains vmcnt (prefetch) + lgkm
    }
#undef ATTN_BODY
#undef STAGE

    // epilogue: O row q=quad*4+reg, col d=dt*16+l16; denom lives at lane l16=q
    float invl = 1.0f / lr1;
    float in0 = __shfl(invl, sb);
    float in1 = __shfl(invl, sb+1);
    float in2 = __shfl(invl, sb+2);
    float in3 = __shfl(invl, sb+3);
    float inv[4] = {in0, in1, in2, in3};
    #pragma unroll
    for (int dt=0; dt<4; ++dt){
        #pragma unroll
        for (int reg=0; reg<4; ++reg){
            int qg = q0 + wave*16 + quad*4 + reg;
            y[((size_t)b*TT + qg)*DD + h*64 + dt*16 + l16] =
                __float2bfloat16(O[dt][reg] * inv[reg]);
        }
    }
}

// ---------------- loss (fp32 logits) ----------------
__global__ void loss_kernel(const float* __restrict__ logits, const int* __restrict__ targets,
                            float* __restrict__ acc){
    int row = blockIdx.x;
    int lane = threadIdx.x;
    int yt = targets[row];
    const float* lp = logits + (size_t)row*VV;
    float e0 = (lane < VV)    ? lp[lane]    : -1e30f;
    float e1 = (lane+64 < VV) ? lp[lane+64] : -1e30f;
    float mx = fmaxf(e0,e1);
    #pragma unroll
    for (int o=32;o;o>>=1) mx = fmaxf(mx, __shfl_xor(mx,o));
    float se = 0.f;
    if (lane < VV)    se += __expf(e0-mx);
    if (lane+64 < VV) se += __expf(e1-mx);
    #pragma unroll
    for (int o=32;o;o>>=1) se += __shfl_xor(se,o);
    if (lane == 0 && yt >= 0){
        float wi = (yt>=78 && yt<96) ? 1.0f : (yt==96 ? 0.1f : 0.0f);
        if (wi > 0.f){
            float ly = lp[yt];
            float nll = -(ly - mx - logf(se));
            atomicAdd(&acc[0], wi*nll);
            atomicAdd(&acc[1], wi);
        }
    }
}

__global__ void fin_loss(const float* __restrict__ acc, float* __restrict__ out){
    out[0] = acc[0]/acc[1];
}

// ---------------- launch ----------------
extern "C" void kernel_launch(void* const* d_in, const int* in_sizes, int n_in,
                              void* d_out, int out_size, void* d_ws, size_t ws_size,
                              hipStream_t stream){
    const int*  idx     = (const int*) d_in[0];
    const int*  targets = (const int*) d_in[1];
    const void* wte     = d_in[2];
    const void* wpe     = d_in[3];
    const void* ln1_w   = d_in[4];
    const void* attn_w  = d_in[5];
    const void* proj_w  = d_in[6];
    const void* ln2_w   = d_in[7];
    const void* fc_w    = d_in[8];
    const void* fcp_w   = d_in[9];
    const void* lnf_w   = d_in[10];
    float* out = (float*)d_out;   // fp32: logits [8192,99] then loss [1]

    // workspace layout (float-slot offsets), total ~96.5 MiB
    float* ws   = (float*)d_ws;
    float* ACC  = ws;
    int*   FLAG = (int*)(ws + 4);
    bf16*  Hb   = (bf16*)(ws + 16);                      // [8192,512]  bf16 (8MB)
    bf16*  X    = (bf16*)(ws + 2097168);                 // [8192,512]  bf16 (8MB, residual)
    bf16*  BIG  = (bf16*)(ws + 6291472);                 // [8192,2048] bf16 (32MB)
    bf16*  WB   = (bf16*)(ws + 14680080);                // converted weights (37.7MB)

    const int ATT_S = 3*DD*DD;        // 786432
    const int PRJ_S = DD*DD;          // 262144
    const int FC_S  = 4*DD*DD;        // 1048576
    bf16* WB_att = WB;
    bf16* WB_prj = WB + (size_t)6*ATT_S;
    bf16* WB_fc  = WB_prj + (size_t)6*PRJ_S;
    bf16* WB_fcp = WB_fc  + (size_t)6*FC_S;

    init_kernel<<<1,1,0,stream>>>((const unsigned int*)ln1_w, ACC, FLAG);
    wconv_kernel<<<(6*ATT_S)/2048,256,0,stream>>>(attn_w, WB_att, 6*ATT_S, FLAG);
    wconv_kernel<<<(6*PRJ_S)/2048,256,0,stream>>>(proj_w, WB_prj, 6*PRJ_S, FLAG);
    wconv_kernel<<<(6*FC_S)/2048,256,0,stream>>>(fc_w,  WB_fc,  6*FC_S, FLAG);
    wconv_kernel<<<(6*FC_S)/2048,256,0,stream>>>(fcp_w, WB_fcp, 6*FC_S, FLAG);
    embed_kernel<<<ROWS,256,0,stream>>>(idx, wte, wpe, X, FLAG);
    for (int l=0; l<LL; ++l){
        ln_kernel<<<ROWS,64,0,stream>>>(X, ln1_w, (size_t)l*DD, Hb, FLAG);
        gemm_mfma<0><<<dim3(3*DD/128, ROWS/128),256,0,stream>>>(Hb, WB_att + (size_t)l*ATT_S,
                                                                nullptr, BIG, ROWS, 3*DD, DD);
        attn_mfma11<<<dim3(BB*HH*32),256,0,stream>>>(BIG, Hb);
        gemm_mfma64<<<dim3(DD/128, ROWS/64),256,0,stream>>>(Hb, WB_prj + (size_t)l*PRJ_S,
                                                            X, ROWS, DD, DD);
        ln_kernel<<<ROWS,64,0,stream>>>(X, ln2_w, (size_t)l*DD, Hb, FLAG);
        gemm_mfma<2><<<dim3(4*DD/128, ROWS/128),256,0,stream>>>(Hb, WB_fc + (size_t)l*FC_S,
                                                                nullptr, BIG, ROWS, 4*DD, DD);
        gemm_mfma64<<<dim3(DD/128, ROWS/64),256,0,stream>>>(BIG, WB_fcp + (size_t)l*FC_S,
                                                            X, ROWS, DD, 4*DD);
    }
    ln_kernel<<<ROWS,64,0,stream>>>(X, lnf_w, 0, Hb, FLAG);
    gemm_nt3<<<dim3((VV+63)/64, ROWS/64),256,0,stream>>>(Hb, wte, 0, out, ROWS, VV, DD, FLAG);
    loss_kernel<<<ROWS,64,0,stream>>>(out, targets, ACC);
    fin_loss<<<1,1,0,stream>>>(ACC, out + (size_t)ROWS*VV);
}

// Round 11
// 1402.423 us; speedup vs baseline: 1.0404x; 1.0404x over previous
//
#include <hip/hip_runtime.h>
#include <hip/hip_bf16.h>
#include <math.h>

#define BB 4
#define TT 2048
#define VV 99
#define DD 512
#define HH 8
#define LL 6
#define DHH 64
#define OFFS 28
#define ROWS (BB*TT)   // 8192

typedef __hip_bfloat16 bf16;
typedef __attribute__((ext_vector_type(8))) short bf16x8;
typedef __attribute__((ext_vector_type(4))) short s16x4;
typedef __attribute__((ext_vector_type(4))) float f32x4;

__device__ __forceinline__ float b2f(bf16 x){ return __bfloat162float(x); }

// async 16B/lane global->LDS. LDS dest = wave-uniform base + lane*16 (m97 pattern).
__device__ __forceinline__ void async_copy16(const void* g, void* l){
    __builtin_amdgcn_global_load_lds(
        (const __attribute__((address_space(1))) unsigned int*)g,
        (__attribute__((address_space(3))) unsigned int*)l, 16, 0, 0);
}

// 32-bit LDS byte offset for DS inline asm (generic -> AS3 cast)
__device__ __forceinline__ unsigned lds_off(const void* p){
    return (unsigned)(size_t)(const __attribute__((address_space(3))) char*)p;
}

// ds_read_b64_tr_b16 cooperative 16-lane transpose; per-lane addr = base + 8*lane.
#define TRD(dst, a, lit) asm volatile("ds_read_b64_tr_b16 %0, %1 offset:" lit \
                                      : "=v"(dst) : "v"(a) : "memory")
#define CAT8(lo, hi) ((bf16x8)__builtin_shufflevector((lo), (hi), 0,1,2,3,4,5,6,7))

__device__ __forceinline__ unsigned pk2(float a, float b){
    return ((unsigned)(unsigned short)__bfloat16_as_short(__float2bfloat16(a)))
         | ((unsigned)(unsigned short)__bfloat16_as_short(__float2bfloat16(b)) << 16);
}

// T1: bijective XCD-aware block remap (requires nwg%8==0; all our grids satisfy).
__device__ __forceinline__ void xcd_swz(int gx, int gy, int &bx, int &by){
    int nwg = gx * gy;
    int orig = by * gx + bx;
    int q = nwg >> 3;
    int nid = (orig & 7) * q + (orig >> 3);
    bx = nid % gx;
    by = nid / gx;
}

// fast tanh via v_exp_f32: tanh(u) = sign(u)*(1 - 2/(e^{2|u|}+1)); inf-safe.
__device__ __forceinline__ float fast_tanh(float u){
    float t = 1.0f - 2.0f/(__expf(2.0f*fabsf(u)) + 1.0f);
    return copysignf(t, u);
}

// mode-dispatched weight read from a raw base + element offset (mode1 = bf16 inputs)
__device__ __forceinline__ float wget(const void* w, int mode, size_t i){
    return mode ? b2f(((const bf16*)w)[i]) : ((const float*)w)[i];
}

// ---------------- init ----------------
__global__ void init_kernel(const unsigned int* __restrict__ ln1_bits, float* __restrict__ acc,
                            int* __restrict__ flag){
    acc[0] = 0.f; acc[1] = 0.f;
    flag[0] = (ln1_bits[0] == 0x3F800000u) ? 0 : 1;
}

// ---------------- weight convert: any-dtype -> bf16, 8 elems/thread ----------------
__global__ __launch_bounds__(256) void wconv_kernel(const void* __restrict__ src,
                                                    bf16* __restrict__ dst, int n,
                                                    const int* __restrict__ flag){
    int mode = flag[0];
    size_t i0 = ((size_t)blockIdx.x*256 + threadIdx.x)*8;
    if (i0 >= (size_t)n) return;
    if (mode == 0){
        const float4* sp = (const float4*)((const float*)src + i0);
        float4 a = sp[0], b = sp[1];
        float f[8] = {a.x,a.y,a.z,a.w, b.x,b.y,b.z,b.w};
        union { short s[8]; uint4 u; } cv;
        #pragma unroll
        for (int k=0;k<8;++k) cv.s[k] = __bfloat16_as_short(__float2bfloat16(f[k]));
        *(uint4*)(dst + i0) = cv.u;
    } else {
        *(uint4*)(dst + i0) = *(const uint4*)((const bf16*)src + i0);
    }
}

// ---------------- embedding (fp32 X) ----------------
__global__ void embed_kernel(const int* __restrict__ idx, const void* __restrict__ wte,
                             const void* __restrict__ wpe, float* __restrict__ x,
                             const int* __restrict__ flag){
    int mode = flag[0];
    int row = blockIdx.x;
    int t = row % TT;
    int tok = idx[row];
    int i = threadIdx.x;
    #pragma unroll
    for (int j = 0; j < 2; ++j){
        int d = i + j*256;
        x[(size_t)row*DD + d] = wget(wte, mode, (size_t)tok*DD + d)
                              + wget(wpe, mode, (size_t)t*DD + d);
    }
}

// ---------------- layernorm: fp32 in, bf16 out ----------------
__global__ void ln_kernel(const float* __restrict__ x, const void* __restrict__ w,
                          size_t woff, bf16* __restrict__ out, const int* __restrict__ flag){
    int mode = flag[0];
    int row = blockIdx.x;
    int lane = threadIdx.x; // 64
    const float* xr = x + (size_t)row*DD;
    float v[8];
    float s = 0.f;
    #pragma unroll
    for (int j=0;j<8;++j){ v[j] = xr[lane + j*64]; s += v[j]; }
    #pragma unroll
    for (int o=32;o;o>>=1) s += __shfl_xor(s,o);
    float mean = s * (1.0f/DD);
    float vs = 0.f;
    #pragma unroll
    for (int j=0;j<8;++j){ float d = v[j]-mean; vs += d*d; }
    #pragma unroll
    for (int o=32;o;o>>=1) vs += __shfl_xor(vs,o);
    float rstd = rsqrtf(vs*(1.0f/DD) + 1e-5f);
    #pragma unroll
    for (int j=0;j<8;++j){
        int d = lane + j*64;
        out[(size_t)row*DD + d] = __float2bfloat16((v[j]-mean)*rstd*wget(w,mode,woff+d));
    }
}

// ---------------- MFMA GEMM 128x128, BK=64 (half the barrier events vs BK=32) ----------------
// C[M,N] = A[M,K] @ W[N,K]^T. XOR chunk swizzle on LDS rows (pre-swizzled global src,
// rule #21): row j slot s holds content chunk s^(j&7) -> conflict-spread ds_read_b128.
// EPI: 0 = bf16 store Cb, 2 = gelu -> bf16 Cb. T1 XCD swizzle kept.
template<int EPI>
__global__ __launch_bounds__(256) void gemm_mfma(const bf16* __restrict__ A,
        const bf16* __restrict__ W, float* __restrict__ C, bf16* __restrict__ Cb,
        int M, int N, int K){
    __shared__ short As[128*64];
    __shared__ short Ws[128*64];
    int tid = threadIdx.x;
    int bx = blockIdx.x, by = blockIdx.y;
    xcd_swz((int)gridDim.x, (int)gridDim.y, bx, by);
    int m0 = by * 128;
    int n0 = bx * 128;
    int lane = tid & 63, wave = tid >> 6;
    int wm = (wave & 1) * 64, wn = (wave >> 1) * 64;
    int quad = lane >> 4, l16 = lane & 15;

    f32x4 acc[4][4] = {};

    // staging: wave w rows w*32..w*32+31, 4 copies of 8 rows each.
    // lane l: row = w*32 + i*8 + (l>>3), slot = l&7, content chunk = (l&7)^((l>>3)&7)
    int srow = wave*32 + (lane >> 3);
    int scol = ((lane&7) ^ ((lane>>3)&7)) * 8;
    const bf16* ga = A + (size_t)(m0 + srow)*K + scol;
    const bf16* gw = W + (size_t)(n0 + srow)*K + scol;
    short* dA = &As[(wave*32)*64];
    short* dW = &Ws[(wave*32)*64];

    for (int k0 = 0; k0 < K; k0 += 64){
        __syncthreads();
        async_copy16(ga + k0,                  dA);
        async_copy16(ga + (size_t)8*K  + k0,   dA + 8*64);
        async_copy16(ga + (size_t)16*K + k0,   dA + 16*64);
        async_copy16(ga + (size_t)24*K + k0,   dA + 24*64);
        async_copy16(gw + k0,                  dW);
        async_copy16(gw + (size_t)8*K  + k0,   dW + 8*64);
        async_copy16(gw + (size_t)16*K + k0,   dW + 16*64);
        async_copy16(gw + (size_t)24*K + k0,   dW + 24*64);
        __syncthreads();

        int sw = l16 & 7;
        #pragma unroll
        for (int s = 0; s < 2; ++s){
            bf16x8 af[4], bfr[4];
            #pragma unroll
            for (int mi=0;mi<4;++mi){
                int r = wm + mi*16 + l16;
                af[mi] = *(const bf16x8*)&As[r*64 + ((((s<<2)|quad) ^ sw)<<3)];
            }
            #pragma unroll
            for (int ni=0;ni<4;++ni){
                int r = wn + ni*16 + l16;
                bfr[ni] = *(const bf16x8*)&Ws[r*64 + ((((s<<2)|quad) ^ sw)<<3)];
            }
            #pragma unroll
            for (int mi=0;mi<4;++mi)
                #pragma unroll
                for (int ni=0;ni<4;++ni)
                    acc[mi][ni] = __builtin_amdgcn_mfma_f32_16x16x32_bf16(af[mi], bfr[ni], acc[mi][ni], 0, 0, 0);
        }
    }

    #pragma unroll
    for (int mi=0;mi<4;++mi){
        #pragma unroll
        for (int ni=0;ni<4;++ni){
            int mg = m0 + wm + mi*16 + quad*4;
            int ng = n0 + wn + ni*16 + l16;
            #pragma unroll
            for (int reg=0;reg<4;++reg){
                float val = acc[mi][ni][reg];
                size_t off = (size_t)(mg+reg)*N + ng;
                if (EPI==0){
                    Cb[off] = __float2bfloat16(val);
                } else {
                    float xx = val;
                    float u = 0.7978845608028654f*(xx + 0.044715f*xx*xx*xx);
                    Cb[off] = __float2bfloat16(0.5f*xx*(1.0f+fast_tanh(u)));
                }
            }
        }
    }
}

// ---------------- MFMA GEMM 64x128, BK=64, swizzled; fp32 += residual ----------------
__global__ __launch_bounds__(256) void gemm_mfma64(const bf16* __restrict__ A,
        const bf16* __restrict__ W, float* __restrict__ C, int M, int N, int K){
    __shared__ short As[64*64];
    __shared__ short Ws[128*64];
    int tid = threadIdx.x;
    int bx = blockIdx.x, by = blockIdx.y;
    xcd_swz((int)gridDim.x, (int)gridDim.y, bx, by);
    int m0 = by * 64;
    int n0 = bx * 128;
    int lane = tid & 63, wave = tid >> 6;
    int wm = (wave & 1) * 32, wn = (wave >> 1) * 64;
    int quad = lane >> 4, l16 = lane & 15;

    f32x4 acc[2][4] = {};

    int scol = ((lane&7) ^ ((lane>>3)&7)) * 8;
    int srowA = wave*16 + (lane >> 3);   // A: wave w rows w*16..+15 (2 copies)
    int srowW = wave*32 + (lane >> 3);   // W: wave w rows w*32..+31 (4 copies)
    const bf16* ga = A + (size_t)(m0 + srowA)*K + scol;
    const bf16* gw = W + (size_t)(n0 + srowW)*K + scol;
    short* dA = &As[(wave*16)*64];
    short* dW = &Ws[(wave*32)*64];

    for (int k0 = 0; k0 < K; k0 += 64){
        __syncthreads();
        async_copy16(ga + k0,                  dA);
        async_copy16(ga + (size_t)8*K  + k0,   dA + 8*64);
        async_copy16(gw + k0,                  dW);
        async_copy16(gw + (size_t)8*K  + k0,   dW + 8*64);
        async_copy16(gw + (size_t)16*K + k0,   dW + 16*64);
        async_copy16(gw + (size_t)24*K + k0,   dW + 24*64);
        __syncthreads();

        int sw = l16 & 7;
        #pragma unroll
        for (int s = 0; s < 2; ++s){
            bf16x8 af[2], bfr[4];
            #pragma unroll
            for (int mi=0;mi<2;++mi){
                int r = wm + mi*16 + l16;
                af[mi] = *(const bf16x8*)&As[r*64 + ((((s<<2)|quad) ^ sw)<<3)];
            }
            #pragma unroll
            for (int ni=0;ni<4;++ni){
                int r = wn + ni*16 + l16;
                bfr[ni] = *(const bf16x8*)&Ws[r*64 + ((((s<<2)|quad) ^ sw)<<3)];
            }
            #pragma unroll
            for (int mi=0;mi<2;++mi)
                #pragma unroll
                for (int ni=0;ni<4;++ni)
                    acc[mi][ni] = __builtin_amdgcn_mfma_f32_16x16x32_bf16(af[mi], bfr[ni], acc[mi][ni], 0, 0, 0);
        }
    }

    #pragma unroll
    for (int mi=0;mi<2;++mi){
        #pragma unroll
        for (int ni=0;ni<4;++ni){
            int mg = m0 + wm + mi*16 + quad*4;
            int ng = n0 + wn + ni*16 + l16;
            #pragma unroll
            for (int reg=0;reg<4;++reg){
                C[(size_t)(mg+reg)*N + ng] += acc[mi][ni][reg];
            }
        }
    }
}

// ---------------- VALU GEMM (logits: N=99), fp32 store ----------------
__global__ __launch_bounds__(256) void gemm_nt3(const bf16* __restrict__ A,
        const void* __restrict__ W, size_t woff, float* __restrict__ C,
        int M, int N, int K, const int* __restrict__ flag){
    int mode = flag[0];
    __shared__ float As[16][64];
    __shared__ float Wt[16][64];
    int m0 = blockIdx.y * 64;
    int n0 = blockIdx.x * 64;
    int t = threadIdx.x;
    int tx = t & 15, ty = t >> 4;
    float acc[4][4] = {};
    int am = t >> 2;
    int ak = (t & 3) * 4;

    for (int k0 = 0; k0 < K; k0 += 16){
        {
            const __hip_bfloat162* ap = (const __hip_bfloat162*)(A + (size_t)(m0+am)*K + k0 + ak);
            __hip_bfloat162 p0 = ap[0], p1 = ap[1];
            float2 f0 = __bfloat1622float2(p0), f1 = __bfloat1622float2(p1);
            As[ak+0][am]=f0.x; As[ak+1][am]=f0.y; As[ak+2][am]=f1.x; As[ak+3][am]=f1.y;
        }
        int wn = n0 + am;
        if (wn < N){
            size_t off = woff + (size_t)wn*K + k0 + ak;
            if (mode == 0){
                float4 wv = *(const float4*)((const float*)W + off);
                Wt[ak+0][am]=wv.x; Wt[ak+1][am]=wv.y; Wt[ak+2][am]=wv.z; Wt[ak+3][am]=wv.w;
            } else {
                const __hip_bfloat162* wp = (const __hip_bfloat162*)((const bf16*)W + off);
                __hip_bfloat162 p0 = wp[0], p1 = wp[1];
                float2 f0 = __bfloat1622float2(p0), f1 = __bfloat1622float2(p1);
                Wt[ak+0][am]=f0.x; Wt[ak+1][am]=f0.y; Wt[ak+2][am]=f1.x; Wt[ak+3][am]=f1.y;
            }
        } else {
            Wt[ak+0][am]=0.f; Wt[ak+1][am]=0.f; Wt[ak+2][am]=0.f; Wt[ak+3][am]=0.f;
        }
        __syncthreads();
        #pragma unroll
        for (int kk=0;kk<16;++kk){
            float a[4], b[4];
            #pragma unroll
            for (int i=0;i<4;++i) a[i]=As[kk][ty*4+i];
            #pragma unroll
            for (int j=0;j<4;++j) b[j]=Wt[kk][tx*4+j];
            #pragma unroll
            for (int i=0;i<4;++i)
                #pragma unroll
                for (int j=0;j<4;++j)
                    acc[i][j] += a[i]*b[j];
        }
        __syncthreads();
    }

    #pragma unroll
    for (int i=0;i<4;++i){
        int m = m0 + ty*4 + i;
        #pragma unroll
        for (int j=0;j<4;++j){
            int n = n0 + tx*4 + j;
            if (n >= N) continue;
            C[(size_t)m*N+n] = acc[i][j];
        }
    }
}

// ---------------- attention v11 (R5/R7-proven) ----------------
__global__ __launch_bounds__(256) void attn_mfma11(const bf16* __restrict__ qkv,
                                                   bf16* __restrict__ y){
    __shared__ __align__(16) short Ks[4][4096];
    __shared__ __align__(16) short Vs[4][4096];
    __shared__ __align__(16) short P2[4][1024];   // per-wave [16 q][64 k]

    int tid = threadIdx.x;
    int lane = tid & 63, wave = tid >> 6;
    int quad = lane >> 4, l16 = lane & 15;

    int bi = blockIdx.x;
    int qt = 31 - (bi >> 5);       // qt-major: all big tiles first
    int bh = bi & 31;
    int h = bh & 7;
    int b = bh >> 3;
    int q0 = qt * 64;
    size_t base = (size_t)b * TT * 1536;

    // Q frags direct from global (row-major, 16B contiguous); B-operand of swapped MFMA.
    const bf16* qrow = qkv + base + (size_t)(q0 + wave*16 + l16)*1536 + h*64;
    bf16x8 aq0 = *(const bf16x8*)(qrow + quad*8);
    bf16x8 aq1 = *(const bf16x8*)(qrow + 32 + quad*8);

    // K staging source (swizzle pre-applied on global src, rule #21)
    int kj  = wave*16 + (lane>>3);
    int kgo = ((lane&7) ^ ((lane>>3)&7)) << 3;
    // V staging source (4x16-subtiled layout for tr-reads)
    int vj  = ((lane>>3)&3)*8 + ((lane>>5)&1)*4 + ((lane>>1)&3);
    int vdo = wave*16 + ((lane&1)<<3);
    const bf16* ks0 = qkv + base + DD   + h*64 + (size_t)kj*1536 + kgo;
    const bf16* vs0 = qkv + base + 2*DD + h*64 + (size_t)vj*1536 + vdo;
    short* kd = &Ks[0][0] + wave*1024;
    short* vd = &Vs[0][0] + wave*1024;

#define STAGE(bb, j0s) { \
    const bf16* kk_ = ks0 + (size_t)(j0s)*1536; \
    const bf16* vv_ = vs0 + (size_t)(j0s)*1536; \
    short* kdd_ = kd + (bb)*4096; \
    short* vdd_ = vd + (bb)*4096; \
    async_copy16(kk_,                    kdd_); \
    async_copy16(kk_ + (size_t)8*1536,   kdd_ + 512); \
    async_copy16(vv_,                    vdd_); \
    async_copy16(vv_ + (size_t)32*1536,  vdd_ + 512); }

    f32x4 O[4] = {};
    float mr1 = -1e30f;   // running max for q=l16
    float lr1 = 0.f;      // running denom for q=l16

    int jbmax = qt + 1; if (jbmax > 31) jbmax = 31;
    int NT = jbmax + 1;

    STAGE(0, 0);
    if (NT > 1) STAGE(1, 64);
    __syncthreads();

    unsigned l8 = (unsigned)(lane << 3);
    unsigned vbase = lds_off(&Vs[0][0]) + l8;
    char* pw = (char*)&P2[wave][0];
    int swz = (l16 & 7) << 4;
    int qg_row = q0 + wave*16 + l16;   // this lane's softmax row
    int sb = (quad<<4) | (quad<<2);    // broadcast source lane base

#define ATTN_BODY(tt) { \
    int t_ = (tt); \
    int j0 = t_ * 64; \
    const short* kb = &Ks[0][0] + (t_&3)*4096; \
    f32x4 s4[4]; \
    _Pragma("unroll") \
    for (int ni=0; ni<4; ++ni){ \
        int R = ni*16 + l16; \
        int ro = R*64; \
        int sw = R & 7; \
        bf16x8 bk0 = *(const bf16x8*)&kb[ro + ((quad       ^ sw)<<3)]; \
        bf16x8 bk1 = *(const bf16x8*)&kb[ro + (((quad + 4) ^ sw)<<3)]; \
        f32x4 z = {}; \
        z = __builtin_amdgcn_mfma_f32_16x16x32_bf16(bk0, aq0, z, 0, 0, 0); \
        z = __builtin_amdgcn_mfma_f32_16x16x32_bf16(bk1, aq1, z, 0, 0, 0); \
        s4[ni] = z; \
    } \
    float sc[4][4]; \
    bool bd = (j0 + 63 > q0 + OFFS); \
    _Pragma("unroll") \
    for (int ni=0; ni<4; ++ni){ \
        _Pragma("unroll") \
        for (int reg=0; reg<4; ++reg){ \
            float v = s4[ni][reg] * 0.125f; \
            if (bd){ \
                int jg = j0 + ni*16 + quad*4 + reg; \
                if (jg > qg_row + OFFS) v = -1e30f; \
            } \
            sc[ni][reg] = v; \
        } \
    } \
    float mn[4]; \
    _Pragma("unroll") \
    for (int ni=0; ni<4; ++ni) \
        mn[ni] = fmaxf(fmaxf(sc[ni][0], sc[ni][1]), fmaxf(sc[ni][2], sc[ni][3])); \
    float m16 = fmaxf(fmaxf(mn[0], mn[1]), fmaxf(mn[2], mn[3])); \
    m16 = fmaxf(m16, __shfl_xor(m16, 16)); \
    m16 = fmaxf(m16, __shfl_xor(m16, 32)); \
    float nm; \
    float alpha1 = 1.0f; \
    if (__all(m16 <= mr1 + 8.0f)){ \
        nm = mr1;            /* defer-max: keep old max, P bounded by e^8 */ \
    } else { \
        nm = fmaxf(mr1, m16); \
        alpha1 = __expf(mr1 - nm); \
        mr1 = nm; \
        float al0 = __shfl(alpha1, sb); \
        float al1 = __shfl(alpha1, sb+1); \
        float al2 = __shfl(alpha1, sb+2); \
        float al3 = __shfl(alpha1, sb+3); \
        _Pragma("unroll") \
        for (int dt=0; dt<4; ++dt){ \
            O[dt][0] *= al0; O[dt][1] *= al1; O[dt][2] *= al2; O[dt][3] *= al3; \
        } \
    } \
    float rsn[4]; \
    _Pragma("unroll") \
    for (int ni=0; ni<4; ++ni){ \
        _Pragma("unroll") \
        for (int reg=0; reg<4; ++reg) \
            sc[ni][reg] = __expf(sc[ni][reg] - nm); \
        rsn[ni] = (sc[ni][0] + sc[ni][1]) + (sc[ni][2] + sc[ni][3]); \
    } \
    float rs1 = (rsn[0] + rsn[1]) + (rsn[2] + rsn[3]); \
    rs1 += __shfl_xor(rs1, 16); \
    rs1 += __shfl_xor(rs1, 32); \
    lr1 = lr1*alpha1 + rs1; \
    __builtin_amdgcn_sched_barrier(0); \
    unsigned va = vbase + (unsigned)((t_&3)*8192); \
    s16x4 t000,t001,t010,t011, t100,t101,t110,t111, \
          t200,t201,t210,t211, t300,t301,t310,t311; \
    TRD(t000, va, "0");    TRD(t001, va, "512");  TRD(t010, va, "1024"); TRD(t011, va, "1536"); \
    TRD(t100, va, "2048"); TRD(t101, va, "2560"); TRD(t110, va, "3072"); TRD(t111, va, "3584"); \
    TRD(t200, va, "4096"); TRD(t201, va, "4608"); TRD(t210, va, "5120"); TRD(t211, va, "5632"); \
    TRD(t300, va, "6144"); TRD(t301, va, "6656"); TRD(t310, va, "7168"); TRD(t311, va, "7680"); \
    _Pragma("unroll") \
    for (int ni=0; ni<4; ++ni){ \
        unsigned lo = pk2(sc[ni][0], sc[ni][1]); \
        unsigned hi = pk2(sc[ni][2], sc[ni][3]); \
        *(uint2*)(pw + (((l16<<7) + (ni<<5) + (quad<<3)) ^ swz)) = make_uint2(lo, hi); \
    } \
    bf16x8 ap0 = *(const bf16x8*)(pw + (((l16<<7)      + (quad<<4)) ^ swz)); \
    bf16x8 ap1 = *(const bf16x8*)(pw + (((l16<<7) + 64 + (quad<<4)) ^ swz)); \
    asm volatile("s_waitcnt lgkmcnt(0)" ::: "memory"); \
    __builtin_amdgcn_sched_barrier(0); \
    O[0] = __builtin_amdgcn_mfma_f32_16x16x32_bf16(ap0, CAT8(t000,t001), O[0], 0, 0, 0); \
    O[1] = __builtin_amdgcn_mfma_f32_16x16x32_bf16(ap0, CAT8(t100,t101), O[1], 0, 0, 0); \
    O[2] = __builtin_amdgcn_mfma_f32_16x16x32_bf16(ap0, CAT8(t200,t201), O[2], 0, 0, 0); \
    O[3] = __builtin_amdgcn_mfma_f32_16x16x32_bf16(ap0, CAT8(t300,t301), O[3], 0, 0, 0); \
    O[0] = __builtin_amdgcn_mfma_f32_16x16x32_bf16(ap1, CAT8(t010,t011), O[0], 0, 0, 0); \
    O[1] = __builtin_amdgcn_mfma_f32_16x16x32_bf16(ap1, CAT8(t110,t111), O[1], 0, 0, 0); \
    O[2] = __builtin_amdgcn_mfma_f32_16x16x32_bf16(ap1, CAT8(t210,t211), O[2], 0, 0, 0); \
    O[3] = __builtin_amdgcn_mfma_f32_16x16x32_bf16(ap1, CAT8(t310,t311), O[3], 0, 0, 0); }

    for (int tp = 0; tp < NT; tp += 2){
        if (tp+2 < NT) STAGE((tp+2)&3, (tp+2)*64);
        if (tp+3 < NT) STAGE((tp+3)&3, (tp+3)*64);
        ATTN_BODY(tp);
        if (tp+1 < NT) ATTN_BODY(tp+1);
        __syncthreads();   // one barrier per PAIR: drains vmcnt (prefetch) + lgkm
    }
#undef ATTN_BODY
#undef STAGE

    // epilogue: O row q=quad*4+reg, col d=dt*16+l16; denom lives at lane l16=q
    float invl = 1.0f / lr1;
    float in0 = __shfl(invl, sb);
    float in1 = __shfl(invl, sb+1);
    float in2 = __shfl(invl, sb+2);
    float in3 = __shfl(invl, sb+3);
    float inv[4] = {in0, in1, in2, in3};
    #pragma unroll
    for (int dt=0; dt<4; ++dt){
        #pragma unroll
        for (int reg=0; reg<4; ++reg){
            int qg = q0 + wave*16 + quad*4 + reg;
            y[((size_t)b*TT + qg)*DD + h*64 + dt*16 + l16] =
                __float2bfloat16(O[dt][reg] * inv[reg]);
        }
    }
}

// ---------------- loss (fp32 logits) ----------------
__global__ void loss_kernel(const float* __restrict__ logits, const int* __restrict__ targets,
                            float* __restrict__ acc){
    int row = blockIdx.x;
    int lane = threadIdx.x;
    int yt = targets[row];
    const float* lp = logits + (size_t)row*VV;
    float e0 = (lane < VV)    ? lp[lane]    : -1e30f;
    float e1 = (lane+64 < VV) ? lp[lane+64] : -1e30f;
    float mx = fmaxf(e0,e1);
    #pragma unroll
    for (int o=32;o;o>>=1) mx = fmaxf(mx, __shfl_xor(mx,o));
    float se = 0.f;
    if (lane < VV)    se += __expf(e0-mx);
    if (lane+64 < VV) se += __expf(e1-mx);
    #pragma unroll
    for (int o=32;o;o>>=1) se += __shfl_xor(se,o);
    if (lane == 0 && yt >= 0){
        float wi = (yt>=78 && yt<96) ? 1.0f : (yt==96 ? 0.1f : 0.0f);
        if (wi > 0.f){
            float ly = lp[yt];
            float nll = -(ly - mx - logf(se));
            atomicAdd(&acc[0], wi*nll);
            atomicAdd(&acc[1], wi);
        }
    }
}

__global__ void fin_loss(const float* __restrict__ acc, float* __restrict__ out){
    out[0] = acc[0]/acc[1];
}

// ---------------- launch ----------------
extern "C" void kernel_launch(void* const* d_in, const int* in_sizes, int n_in,
                              void* d_out, int out_size, void* d_ws, size_t ws_size,
                              hipStream_t stream){
    const int*  idx     = (const int*) d_in[0];
    const int*  targets = (const int*) d_in[1];
    const void* wte     = d_in[2];
    const void* wpe     = d_in[3];
    const void* ln1_w   = d_in[4];
    const void* attn_w  = d_in[5];
    const void* proj_w  = d_in[6];
    const void* ln2_w   = d_in[7];
    const void* fc_w    = d_in[8];
    const void* fcp_w   = d_in[9];
    const void* lnf_w   = d_in[10];
    float* out = (float*)d_out;   // fp32: logits [8192,99] then loss [1]

    // workspace layout (float-slot offsets), total ~96.5 MiB
    float* ws   = (float*)d_ws;
    float* ACC  = ws;
    int*   FLAG = (int*)(ws + 4);
    bf16*  Hb   = (bf16*)(ws + 16);                      // [8192,512]  bf16 (8MB)
    float* X    = ws + 2097168;                          // [8192,512]  fp32 (16MB)
    bf16*  BIG  = (bf16*)(ws + 6291472);                 // [8192,2048] bf16 (32MB)
    bf16*  WB   = (bf16*)(ws + 14680080);                // converted weights (37.7MB)

    const int ATT_S = 3*DD*DD;        // 786432
    const int PRJ_S = DD*DD;          // 262144
    const int FC_S  = 4*DD*DD;        // 1048576
    bf16* WB_att = WB;
    bf16* WB_prj = WB + (size_t)6*ATT_S;
    bf16* WB_fc  = WB_prj + (size_t)6*PRJ_S;
    bf16* WB_fcp = WB_fc  + (size_t)6*FC_S;

    init_kernel<<<1,1,0,stream>>>((const unsigned int*)ln1_w, ACC, FLAG);
    wconv_kernel<<<(6*ATT_S)/2048,256,0,stream>>>(attn_w, WB_att, 6*ATT_S, FLAG);
    wconv_kernel<<<(6*PRJ_S)/2048,256,0,stream>>>(proj_w, WB_prj, 6*PRJ_S, FLAG);
    wconv_kernel<<<(6*FC_S)/2048,256,0,stream>>>(fc_w,  WB_fc,  6*FC_S, FLAG);
    wconv_kernel<<<(6*FC_S)/2048,256,0,stream>>>(fcp_w, WB_fcp, 6*FC_S, FLAG);
    embed_kernel<<<ROWS,256,0,stream>>>(idx, wte, wpe, X, FLAG);
    for (int l=0; l<LL; ++l){
        ln_kernel<<<ROWS,64,0,stream>>>(X, ln1_w, (size_t)l*DD, Hb, FLAG);
        gemm_mfma<0><<<dim3(3*DD/128, ROWS/128),256,0,stream>>>(Hb, WB_att + (size_t)l*ATT_S,
                                                                nullptr, BIG, ROWS, 3*DD, DD);
        attn_mfma11<<<dim3(BB*HH*32),256,0,stream>>>(BIG, Hb);
        gemm_mfma64<<<dim3(DD/128, ROWS/64),256,0,stream>>>(Hb, WB_prj + (size_t)l*PRJ_S,
                                                            X, ROWS, DD, DD);
        ln_kernel<<<ROWS,64,0,stream>>>(X, ln2_w, (size_t)l*DD, Hb, FLAG);
        gemm_mfma<2><<<dim3(4*DD/128, ROWS/128),256,0,stream>>>(Hb, WB_fc + (size_t)l*FC_S,
                                                                nullptr, BIG, ROWS, 4*DD, DD);
        gemm_mfma64<<<dim3(DD/128, ROWS/64),256,0,stream>>>(BIG, WB_fcp + (size_t)l*FC_S,
                                                            X, ROWS, DD, 4*DD);
    }
    ln_kernel<<<ROWS,64,0,stream>>>(X, lnf_w, 0, Hb, FLAG);
    gemm_nt3<<<dim3((VV+63)/64, ROWS/64),256,0,stream>>>(Hb, wte, 0, out, ROWS, VV, DD, FLAG);
    loss_kernel<<<ROWS,64,0,stream>>>(out, targets, ACC);
    fin_loss<<<1,1,0,stream>>>(ACC, out + (size_t)ROWS*VV);
}

// Round 12
// 1329.341 us; speedup vs baseline: 1.0976x; 1.0550x over previous
//
#include <hip/hip_runtime.h>
#include <hip/hip_bf16.h>
#include <math.h>

#define BB 4
#define TT 2048
#define VV 99
#define DD 512
#define HH 8
#define LL 6
#define DHH 64
#define OFFS 28
#define ROWS (BB*TT)   // 8192

typedef __hip_bfloat16 bf16;
typedef __attribute__((ext_vector_type(8))) short bf16x8;
typedef __attribute__((ext_vector_type(4))) short s16x4;
typedef __attribute__((ext_vector_type(4))) float f32x4;

__device__ __forceinline__ float b2f(bf16 x){ return __bfloat162float(x); }

// async 16B/lane global->LDS. LDS dest = wave-uniform base + lane*16 (m97 pattern).
__device__ __forceinline__ void async_copy16(const void* g, void* l){
    __builtin_amdgcn_global_load_lds(
        (const __attribute__((address_space(1))) unsigned int*)g,
        (__attribute__((address_space(3))) unsigned int*)l, 16, 0, 0);
}

// 32-bit LDS byte offset for DS inline asm (generic -> AS3 cast)
__device__ __forceinline__ unsigned lds_off(const void* p){
    return (unsigned)(size_t)(const __attribute__((address_space(3))) char*)p;
}

// ds_read_b64_tr_b16 cooperative 16-lane transpose; per-lane addr = base + 8*lane.
#define TRD(dst, a, lit) asm volatile("ds_read_b64_tr_b16 %0, %1 offset:" lit \
                                      : "=v"(dst) : "v"(a) : "memory")
#define CAT8(lo, hi) ((bf16x8)__builtin_shufflevector((lo), (hi), 0,1,2,3,4,5,6,7))

__device__ __forceinline__ unsigned pk2(float a, float b){
    return ((unsigned)(unsigned short)__bfloat16_as_short(__float2bfloat16(a)))
         | ((unsigned)(unsigned short)__bfloat16_as_short(__float2bfloat16(b)) << 16);
}

// T1: bijective XCD-aware block remap (requires nwg%8==0; all our grids satisfy).
__device__ __forceinline__ void xcd_swz(int gx, int gy, int &bx, int &by){
    int nwg = gx * gy;
    int orig = by * gx + bx;
    int q = nwg >> 3;
    int nid = (orig & 7) * q + (orig >> 3);
    bx = nid % gx;
    by = nid / gx;
}

// fast tanh via v_exp_f32: tanh(u) = sign(u)*(1 - 2/(e^{2|u|}+1)); inf-safe.
__device__ __forceinline__ float fast_tanh(float u){
    float t = 1.0f - 2.0f/(__expf(2.0f*fabsf(u)) + 1.0f);
    return copysignf(t, u);
}

// mode-dispatched weight read from a raw base + element offset (mode1 = bf16 inputs)
__device__ __forceinline__ float wget(const void* w, int mode, size_t i){
    return mode ? b2f(((const bf16*)w)[i]) : ((const float*)w)[i];
}

// ---------------- init ----------------
__global__ void init_kernel(const unsigned int* __restrict__ ln1_bits, float* __restrict__ acc,
                            int* __restrict__ flag){
    acc[0] = 0.f; acc[1] = 0.f;
    flag[0] = (ln1_bits[0] == 0x3F800000u) ? 0 : 1;
}

// ---------------- weight convert: any-dtype -> bf16, 8 elems/thread ----------------
__global__ __launch_bounds__(256) void wconv_kernel(const void* __restrict__ src,
                                                    bf16* __restrict__ dst, int n,
                                                    const int* __restrict__ flag){
    int mode = flag[0];
    size_t i0 = ((size_t)blockIdx.x*256 + threadIdx.x)*8;
    if (i0 >= (size_t)n) return;
    if (mode == 0){
        const float4* sp = (const float4*)((const float*)src + i0);
        float4 a = sp[0], b = sp[1];
        float f[8] = {a.x,a.y,a.z,a.w, b.x,b.y,b.z,b.w};
        union { short s[8]; uint4 u; } cv;
        #pragma unroll
        for (int k=0;k<8;++k) cv.s[k] = __bfloat16_as_short(__float2bfloat16(f[k]));
        *(uint4*)(dst + i0) = cv.u;
    } else {
        *(uint4*)(dst + i0) = *(const uint4*)((const bf16*)src + i0);
    }
}

// ---------------- embedding (fp32 X) ----------------
__global__ void embed_kernel(const int* __restrict__ idx, const void* __restrict__ wte,
                             const void* __restrict__ wpe, float* __restrict__ x,
                             const int* __restrict__ flag){
    int mode = flag[0];
    int row = blockIdx.x;
    int t = row % TT;
    int tok = idx[row];
    int i = threadIdx.x;
    #pragma unroll
    for (int j = 0; j < 2; ++j){
        int d = i + j*256;
        x[(size_t)row*DD + d] = wget(wte, mode, (size_t)tok*DD + d)
                              + wget(wpe, mode, (size_t)t*DD + d);
    }
}

// ---------------- layernorm: fp32 in, bf16 out ----------------
__global__ void ln_kernel(const float* __restrict__ x, const void* __restrict__ w,
                          size_t woff, bf16* __restrict__ out, const int* __restrict__ flag){
    int mode = flag[0];
    int row = blockIdx.x;
    int lane = threadIdx.x; // 64
    const float* xr = x + (size_t)row*DD;
    float v[8];
    float s = 0.f;
    #pragma unroll
    for (int j=0;j<8;++j){ v[j] = xr[lane + j*64]; s += v[j]; }
    #pragma unroll
    for (int o=32;o;o>>=1) s += __shfl_xor(s,o);
    float mean = s * (1.0f/DD);
    float vs = 0.f;
    #pragma unroll
    for (int j=0;j<8;++j){ float d = v[j]-mean; vs += d*d; }
    #pragma unroll
    for (int o=32;o;o>>=1) vs += __shfl_xor(vs,o);
    float rstd = rsqrtf(vs*(1.0f/DD) + 1e-5f);
    #pragma unroll
    for (int j=0;j<8;++j){
        int d = lane + j*64;
        out[(size_t)row*DD + d] = __float2bfloat16((v[j]-mean)*rstd*wget(w,mode,woff+d));
    }
}

// ---------------- MFMA GEMM 128x128, BK=64 ----------------
// C[M,N] = A[M,K] @ W[N,K]^T. XOR chunk swizzle on LDS rows (pre-swizzled global src).
// EPI: 0 = bf16 store Cb, 2 = gelu -> bf16 Cb. T1 XCD swizzle kept.
template<int EPI>
__global__ __launch_bounds__(256) void gemm_mfma(const bf16* __restrict__ A,
        const bf16* __restrict__ W, float* __restrict__ C, bf16* __restrict__ Cb,
        int M, int N, int K){
    __shared__ short As[128*64];
    __shared__ short Ws[128*64];
    int tid = threadIdx.x;
    int bx = blockIdx.x, by = blockIdx.y;
    xcd_swz((int)gridDim.x, (int)gridDim.y, bx, by);
    int m0 = by * 128;
    int n0 = bx * 128;
    int lane = tid & 63, wave = tid >> 6;
    int wm = (wave & 1) * 64, wn = (wave >> 1) * 64;
    int quad = lane >> 4, l16 = lane & 15;

    f32x4 acc[4][4] = {};

    int srow = wave*32 + (lane >> 3);
    int scol = ((lane&7) ^ ((lane>>3)&7)) * 8;
    const bf16* ga = A + (size_t)(m0 + srow)*K + scol;
    const bf16* gw = W + (size_t)(n0 + srow)*K + scol;
    short* dA = &As[(wave*32)*64];
    short* dW = &Ws[(wave*32)*64];

    for (int k0 = 0; k0 < K; k0 += 64){
        __syncthreads();
        async_copy16(ga + k0,                  dA);
        async_copy16(ga + (size_t)8*K  + k0,   dA + 8*64);
        async_copy16(ga + (size_t)16*K + k0,   dA + 16*64);
        async_copy16(ga + (size_t)24*K + k0,   dA + 24*64);
        async_copy16(gw + k0,                  dW);
        async_copy16(gw + (size_t)8*K  + k0,   dW + 8*64);
        async_copy16(gw + (size_t)16*K + k0,   dW + 16*64);
        async_copy16(gw + (size_t)24*K + k0,   dW + 24*64);
        __syncthreads();

        int sw = l16 & 7;
        #pragma unroll
        for (int s = 0; s < 2; ++s){
            bf16x8 af[4], bfr[4];
            #pragma unroll
            for (int mi=0;mi<4;++mi){
                int r = wm + mi*16 + l16;
                af[mi] = *(const bf16x8*)&As[r*64 + ((((s<<2)|quad) ^ sw)<<3)];
            }
            #pragma unroll
            for (int ni=0;ni<4;++ni){
                int r = wn + ni*16 + l16;
                bfr[ni] = *(const bf16x8*)&Ws[r*64 + ((((s<<2)|quad) ^ sw)<<3)];
            }
            #pragma unroll
            for (int mi=0;mi<4;++mi)
                #pragma unroll
                for (int ni=0;ni<4;++ni)
                    acc[mi][ni] = __builtin_amdgcn_mfma_f32_16x16x32_bf16(af[mi], bfr[ni], acc[mi][ni], 0, 0, 0);
        }
    }

    #pragma unroll
    for (int mi=0;mi<4;++mi){
        #pragma unroll
        for (int ni=0;ni<4;++ni){
            int mg = m0 + wm + mi*16 + quad*4;
            int ng = n0 + wn + ni*16 + l16;
            #pragma unroll
            for (int reg=0;reg<4;++reg){
                float val = acc[mi][ni][reg];
                size_t off = (size_t)(mg+reg)*N + ng;
                if (EPI==0){
                    Cb[off] = __float2bfloat16(val);
                } else {
                    float xx = val;
                    float u = 0.7978845608028654f*(xx + 0.044715f*xx*xx*xx);
                    Cb[off] = __float2bfloat16(0.5f*xx*(1.0f+fast_tanh(u)));
                }
            }
        }
    }
}

// ---------------- MFMA GEMM 64x128, BK=64, swizzled; fp32 += residual ----------------
__global__ __launch_bounds__(256) void gemm_mfma64(const bf16* __restrict__ A,
        const bf16* __restrict__ W, float* __restrict__ C, int M, int N, int K){
    __shared__ short As[64*64];
    __shared__ short Ws[128*64];
    int tid = threadIdx.x;
    int bx = blockIdx.x, by = blockIdx.y;
    xcd_swz((int)gridDim.x, (int)gridDim.y, bx, by);
    int m0 = by * 64;
    int n0 = bx * 128;
    int lane = tid & 63, wave = tid >> 6;
    int wm = (wave & 1) * 32, wn = (wave >> 1) * 64;
    int quad = lane >> 4, l16 = lane & 15;

    f32x4 acc[2][4] = {};

    int scol = ((lane&7) ^ ((lane>>3)&7)) * 8;
    int srowA = wave*16 + (lane >> 3);   // A: wave w rows w*16..+15 (2 copies)
    int srowW = wave*32 + (lane >> 3);   // W: wave w rows w*32..+31 (4 copies)
    const bf16* ga = A + (size_t)(m0 + srowA)*K + scol;
    const bf16* gw = W + (size_t)(n0 + srowW)*K + scol;
    short* dA = &As[(wave*16)*64];
    short* dW = &Ws[(wave*32)*64];

    for (int k0 = 0; k0 < K; k0 += 64){
        __syncthreads();
        async_copy16(ga + k0,                  dA);
        async_copy16(ga + (size_t)8*K  + k0,   dA + 8*64);
        async_copy16(gw + k0,                  dW);
        async_copy16(gw + (size_t)8*K  + k0,   dW + 8*64);
        async_copy16(gw + (size_t)16*K + k0,   dW + 16*64);
        async_copy16(gw + (size_t)24*K + k0,   dW + 24*64);
        __syncthreads();

        int sw = l16 & 7;
        #pragma unroll
        for (int s = 0; s < 2; ++s){
            bf16x8 af[2], bfr[4];
            #pragma unroll
            for (int mi=0;mi<2;++mi){
                int r = wm + mi*16 + l16;
                af[mi] = *(const bf16x8*)&As[r*64 + ((((s<<2)|quad) ^ sw)<<3)];
            }
            #pragma unroll
            for (int ni=0;ni<4;++ni){
                int r = wn + ni*16 + l16;
                bfr[ni] = *(const bf16x8*)&Ws[r*64 + ((((s<<2)|quad) ^ sw)<<3)];
            }
            #pragma unroll
            for (int mi=0;mi<2;++mi)
                #pragma unroll
                for (int ni=0;ni<4;++ni)
                    acc[mi][ni] = __builtin_amdgcn_mfma_f32_16x16x32_bf16(af[mi], bfr[ni], acc[mi][ni], 0, 0, 0);
        }
    }

    #pragma unroll
    for (int mi=0;mi<2;++mi){
        #pragma unroll
        for (int ni=0;ni<4;++ni){
            int mg = m0 + wm + mi*16 + quad*4;
            int ng = n0 + wn + ni*16 + l16;
            #pragma unroll
            for (int reg=0;reg<4;++reg){
                C[(size_t)(mg+reg)*N + ng] += acc[mi][ni][reg];
            }
        }
    }
}

// ---------------- VALU GEMM (logits: N=99), fp32 store ----------------
__global__ __launch_bounds__(256) void gemm_nt3(const bf16* __restrict__ A,
        const void* __restrict__ W, size_t woff, float* __restrict__ C,
        int M, int N, int K, const int* __restrict__ flag){
    int mode = flag[0];
    __shared__ float As[16][64];
    __shared__ float Wt[16][64];
    int m0 = blockIdx.y * 64;
    int n0 = blockIdx.x * 64;
    int t = threadIdx.x;
    int tx = t & 15, ty = t >> 4;
    float acc[4][4] = {};
    int am = t >> 2;
    int ak = (t & 3) * 4;

    for (int k0 = 0; k0 < K; k0 += 16){
        {
            const __hip_bfloat162* ap = (const __hip_bfloat162*)(A + (size_t)(m0+am)*K + k0 + ak);
            __hip_bfloat162 p0 = ap[0], p1 = ap[1];
            float2 f0 = __bfloat1622float2(p0), f1 = __bfloat1622float2(p1);
            As[ak+0][am]=f0.x; As[ak+1][am]=f0.y; As[ak+2][am]=f1.x; As[ak+3][am]=f1.y;
        }
        int wn = n0 + am;
        if (wn < N){
            size_t off = woff + (size_t)wn*K + k0 + ak;
            if (mode == 0){
                float4 wv = *(const float4*)((const float*)W + off);
                Wt[ak+0][am]=wv.x; Wt[ak+1][am]=wv.y; Wt[ak+2][am]=wv.z; Wt[ak+3][am]=wv.w;
            } else {
                const __hip_bfloat162* wp = (const __hip_bfloat162*)((const bf16*)W + off);
                __hip_bfloat162 p0 = wp[0], p1 = wp[1];
                float2 f0 = __bfloat1622float2(p0), f1 = __bfloat1622float2(p1);
                Wt[ak+0][am]=f0.x; Wt[ak+1][am]=f0.y; Wt[ak+2][am]=f1.x; Wt[ak+3][am]=f1.y;
            }
        } else {
            Wt[ak+0][am]=0.f; Wt[ak+1][am]=0.f; Wt[ak+2][am]=0.f; Wt[ak+3][am]=0.f;
        }
        __syncthreads();
        #pragma unroll
        for (int kk=0;kk<16;++kk){
            float a[4], b[4];
            #pragma unroll
            for (int i=0;i<4;++i) a[i]=As[kk][ty*4+i];
            #pragma unroll
            for (int j=0;j<4;++j) b[j]=Wt[kk][tx*4+j];
            #pragma unroll
            for (int i=0;i<4;++i)
                #pragma unroll
                for (int j=0;j<4;++j)
                    acc[i][j] += a[i]*b[j];
        }
        __syncthreads();
    }

    #pragma unroll
    for (int i=0;i<4;++i){
        int m = m0 + ty*4 + i;
        #pragma unroll
        for (int j=0;j<4;++j){
            int n = n0 + tx*4 + j;
            if (n >= N) continue;
            C[(size_t)m*N+n] = acc[i][j];
        }
    }
}

// ---------------- attention v13: 8 waves / QBLK=128 (occupancy 25% -> 50% cap) ----------------
// One wg per (b,h,qtile128), qt-major grid. 8 waves each own 16 q rows; K/V tiles
// (KVBLK=64) shared by all 8 waves -> staging bytes per unit compute halved.
// Same 4-buffer pair-unrolled schedule, swapped QK^T, defer-max, verified layouts.
// LDS 80KB -> 2 wg/CU x 8 waves = 16 waves/CU.
__global__ __launch_bounds__(512) void attn_mfma13(const bf16* __restrict__ qkv,
                                                   bf16* __restrict__ y){
    __shared__ __align__(16) short Ks[4][4096];
    __shared__ __align__(16) short Vs[4][4096];
    __shared__ __align__(16) short P2[8][1024];   // per-wave [16 q][64 k]

    int tid = threadIdx.x;
    int lane = tid & 63, wave = tid >> 6;   // wave 0..7
    int quad = lane >> 4, l16 = lane & 15;

    int bi = blockIdx.x;
    int qt = 15 - (bi >> 5);       // qt-major: all big tiles first (16 qtiles of 128)
    int bh = bi & 31;
    int h = bh & 7;
    int b = bh >> 3;
    int q0 = qt * 128;
    size_t base = (size_t)b * TT * 1536;

    // Q frags direct from global; wave owns q rows q0 + wave*16 .. +15
    const bf16* qrow = qkv + base + (size_t)(q0 + wave*16 + l16)*1536 + h*64;
    bf16x8 aq0 = *(const bf16x8*)(qrow + quad*8);
    bf16x8 aq1 = *(const bf16x8*)(qrow + 32 + quad*8);

    // K staging: wave covers rows wave*8..+7 (one copy). slot s = lane&7,
    // content chunk = s ^ (j&7); j&7 = (lane>>3)&7 since wave*8 % 8 == 0.
    int kj  = wave*8 + (lane>>3);
    int kgo = ((lane&7) ^ ((lane>>3)&7)) << 3;
    // V staging: chunk c = wave*64 + lane -> dt = wave>>1, jb = wave&1,
    // r = (lane>>5)&1, qd = (lane>>3)&3, jj = (lane>>1)&3, d16h = lane&1
    // j = jb*32 + qd*8 + r*4 + jj ; d = dt*16 + d16h*8   (v9-verified e(j,d) layout)
    int vj  = (wave&1)*32 + ((lane>>3)&3)*8 + ((lane>>5)&1)*4 + ((lane>>1)&3);
    int vdo = (wave>>1)*16 + ((lane&1)<<3);
    const bf16* ks0 = qkv + base + DD   + h*64 + (size_t)kj*1536 + kgo;
    const bf16* vs0 = qkv + base + 2*DD + h*64 + (size_t)vj*1536 + vdo;
    short* kd = &Ks[0][0] + wave*512;
    short* vd = &Vs[0][0] + wave*512;

#define STAGE(bb, j0s) { \
    async_copy16(ks0 + (size_t)(j0s)*1536, kd + (bb)*4096); \
    async_copy16(vs0 + (size_t)(j0s)*1536, vd + (bb)*4096); }

    f32x4 O[4] = {};
    float mr1 = -1e30f;   // running max for q = q0 + wave*16 + l16
    float lr1 = 0.f;      // running denom

    int jbmax = (q0 + 127 + OFFS) >> 6; if (jbmax > 31) jbmax = 31;
    int NT = jbmax + 1;

    STAGE(0, 0);
    if (NT > 1) STAGE(1, 64);
    __syncthreads();

    unsigned l8 = (unsigned)(lane << 3);
    unsigned vbase = lds_off(&Vs[0][0]) + l8;
    char* pw = (char*)&P2[wave][0];
    int swz = (l16 & 7) << 4;
    int qg_row = q0 + wave*16 + l16;   // this lane's softmax row
    int sb = (quad<<4) | (quad<<2);    // broadcast source lane base

#define ATTN_BODY(tt) { \
    int t_ = (tt); \
    int j0 = t_ * 64; \
    const short* kb = &Ks[0][0] + (t_&3)*4096; \
    f32x4 s4[4]; \
    _Pragma("unroll") \
    for (int ni=0; ni<4; ++ni){ \
        int R = ni*16 + l16; \
        int ro = R*64; \
        int sw = R & 7; \
        bf16x8 bk0 = *(const bf16x8*)&kb[ro + ((quad       ^ sw)<<3)]; \
        bf16x8 bk1 = *(const bf16x8*)&kb[ro + (((quad + 4) ^ sw)<<3)]; \
        f32x4 z = {}; \
        z = __builtin_amdgcn_mfma_f32_16x16x32_bf16(bk0, aq0, z, 0, 0, 0); \
        z = __builtin_amdgcn_mfma_f32_16x16x32_bf16(bk1, aq1, z, 0, 0, 0); \
        s4[ni] = z; \
    } \
    float sc[4][4]; \
    bool bd = (j0 + 63 > qg_row + OFFS); \
    _Pragma("unroll") \
    for (int ni=0; ni<4; ++ni){ \
        _Pragma("unroll") \
        for (int reg=0; reg<4; ++reg){ \
            float v = s4[ni][reg] * 0.125f; \
            if (bd){ \
                int jg = j0 + ni*16 + quad*4 + reg; \
                if (jg > qg_row + OFFS) v = -1e30f; \
            } \
            sc[ni][reg] = v; \
        } \
    } \
    float mn[4]; \
    _Pragma("unroll") \
    for (int ni=0; ni<4; ++ni) \
        mn[ni] = fmaxf(fmaxf(sc[ni][0], sc[ni][1]), fmaxf(sc[ni][2], sc[ni][3])); \
    float m16 = fmaxf(fmaxf(mn[0], mn[1]), fmaxf(mn[2], mn[3])); \
    m16 = fmaxf(m16, __shfl_xor(m16, 16)); \
    m16 = fmaxf(m16, __shfl_xor(m16, 32)); \
    float nm; \
    float alpha1 = 1.0f; \
    if (__all(m16 <= mr1 + 8.0f)){ \
        nm = mr1;            /* defer-max: keep old max, P bounded by e^8 */ \
    } else { \
        nm = fmaxf(mr1, m16); \
        alpha1 = __expf(mr1 - nm); \
        mr1 = nm; \
        float al0 = __shfl(alpha1, sb); \
        float al1 = __shfl(alpha1, sb+1); \
        float al2 = __shfl(alpha1, sb+2); \
        float al3 = __shfl(alpha1, sb+3); \
        _Pragma("unroll") \
        for (int dt=0; dt<4; ++dt){ \
            O[dt][0] *= al0; O[dt][1] *= al1; O[dt][2] *= al2; O[dt][3] *= al3; \
        } \
    } \
    float rsn[4]; \
    _Pragma("unroll") \
    for (int ni=0; ni<4; ++ni){ \
        _Pragma("unroll") \
        for (int reg=0; reg<4; ++reg) \
            sc[ni][reg] = __expf(sc[ni][reg] - nm); \
        rsn[ni] = (sc[ni][0] + sc[ni][1]) + (sc[ni][2] + sc[ni][3]); \
    } \
    float rs1 = (rsn[0] + rsn[1]) + (rsn[2] + rsn[3]); \
    rs1 += __shfl_xor(rs1, 16); \
    rs1 += __shfl_xor(rs1, 32); \
    lr1 = lr1*alpha1 + rs1; \
    __builtin_amdgcn_sched_barrier(0); \
    unsigned va = vbase + (unsigned)((t_&3)*8192); \
    s16x4 t000,t001,t010,t011, t100,t101,t110,t111, \
          t200,t201,t210,t211, t300,t301,t310,t311; \
    TRD(t000, va, "0");    TRD(t001, va, "512");  TRD(t010, va, "1024"); TRD(t011, va, "1536"); \
    TRD(t100, va, "2048"); TRD(t101, va, "2560"); TRD(t110, va, "3072"); TRD(t111, va, "3584"); \
    TRD(t200, va, "4096"); TRD(t201, va, "4608"); TRD(t210, va, "5120"); TRD(t211, va, "5632"); \
    TRD(t300, va, "6144"); TRD(t301, va, "6656"); TRD(t310, va, "7168"); TRD(t311, va, "7680"); \
    _Pragma("unroll") \
    for (int ni=0; ni<4; ++ni){ \
        unsigned lo = pk2(sc[ni][0], sc[ni][1]); \
        unsigned hi = pk2(sc[ni][2], sc[ni][3]); \
        *(uint2*)(pw + (((l16<<7) + (ni<<5) + (quad<<3)) ^ swz)) = make_uint2(lo, hi); \
    } \
    bf16x8 ap0 = *(const bf16x8*)(pw + (((l16<<7)      + (quad<<4)) ^ swz)); \
    bf16x8 ap1 = *(const bf16x8*)(pw + (((l16<<7) + 64 + (quad<<4)) ^ swz)); \
    asm volatile("s_waitcnt lgkmcnt(0)" ::: "memory"); \
    __builtin_amdgcn_sched_barrier(0); \
    O[0] = __builtin_amdgcn_mfma_f32_16x16x32_bf16(ap0, CAT8(t000,t001), O[0], 0, 0, 0); \
    O[1] = __builtin_amdgcn_mfma_f32_16x16x32_bf16(ap0, CAT8(t100,t101), O[1], 0, 0, 0); \
    O[2] = __builtin_amdgcn_mfma_f32_16x16x32_bf16(ap0, CAT8(t200,t201), O[2], 0, 0, 0); \
    O[3] = __builtin_amdgcn_mfma_f32_16x16x32_bf16(ap0, CAT8(t300,t301), O[3], 0, 0, 0); \
    O[0] = __builtin_amdgcn_mfma_f32_16x16x32_bf16(ap1, CAT8(t010,t011), O[0], 0, 0, 0); \
    O[1] = __builtin_amdgcn_mfma_f32_16x16x32_bf16(ap1, CAT8(t110,t111), O[1], 0, 0, 0); \
    O[2] = __builtin_amdgcn_mfma_f32_16x16x32_bf16(ap1, CAT8(t210,t211), O[2], 0, 0, 0); \
    O[3] = __builtin_amdgcn_mfma_f32_16x16x32_bf16(ap1, CAT8(t310,t311), O[3], 0, 0, 0); }

    for (int tp = 0; tp < NT; tp += 2){
        if (tp+2 < NT) STAGE((tp+2)&3, (tp+2)*64);
        if (tp+3 < NT) STAGE((tp+3)&3, (tp+3)*64);
        ATTN_BODY(tp);
        if (tp+1 < NT) ATTN_BODY(tp+1);
        __syncthreads();   // one barrier per PAIR: drains vmcnt (prefetch) + lgkm
    }
#undef ATTN_BODY
#undef STAGE

    // epilogue: O row q=quad*4+reg, col d=dt*16+l16; denom lives at lane l16=q
    float invl = 1.0f / lr1;
    float in0 = __shfl(invl, sb);
    float in1 = __shfl(invl, sb+1);
    float in2 = __shfl(invl, sb+2);
    float in3 = __shfl(invl, sb+3);
    float inv[4] = {in0, in1, in2, in3};
    #pragma unroll
    for (int dt=0; dt<4; ++dt){
        #pragma unroll
        for (int reg=0; reg<4; ++reg){
            int qg = q0 + wave*16 + quad*4 + reg;
            y[((size_t)b*TT + qg)*DD + h*64 + dt*16 + l16] =
                __float2bfloat16(O[dt][reg] * inv[reg]);
        }
    }
}

// ---------------- loss (fp32 logits) ----------------
__global__ void loss_kernel(const float* __restrict__ logits, const int* __restrict__ targets,
                            float* __restrict__ acc){
    int row = blockIdx.x;
    int lane = threadIdx.x;
    int yt = targets[row];
    const float* lp = logits + (size_t)row*VV;
    float e0 = (lane < VV)    ? lp[lane]    : -1e30f;
    float e1 = (lane+64 < VV) ? lp[lane+64] : -1e30f;
    float mx = fmaxf(e0,e1);
    #pragma unroll
    for (int o=32;o;o>>=1) mx = fmaxf(mx, __shfl_xor(mx,o));
    float se = 0.f;
    if (lane < VV)    se += __expf(e0-mx);
    if (lane+64 < VV) se += __expf(e1-mx);
    #pragma unroll
    for (int o=32;o;o>>=1) se += __shfl_xor(se,o);
    if (lane == 0 && yt >= 0){
        float wi = (yt>=78 && yt<96) ? 1.0f : (yt==96 ? 0.1f : 0.0f);
        if (wi > 0.f){
            float ly = lp[yt];
            float nll = -(ly - mx - logf(se));
            atomicAdd(&acc[0], wi*nll);
            atomicAdd(&acc[1], wi);
        }
    }
}

__global__ void fin_loss(const float* __restrict__ acc, float* __restrict__ out){
    out[0] = acc[0]/acc[1];
}

// ---------------- launch ----------------
extern "C" void kernel_launch(void* const* d_in, const int* in_sizes, int n_in,
                              void* d_out, int out_size, void* d_ws, size_t ws_size,
                              hipStream_t stream){
    const int*  idx     = (const int*) d_in[0];
    const int*  targets = (const int*) d_in[1];
    const void* wte     = d_in[2];
    const void* wpe     = d_in[3];
    const void* ln1_w   = d_in[4];
    const void* attn_w  = d_in[5];
    const void* proj_w  = d_in[6];
    const void* ln2_w   = d_in[7];
    const void* fc_w    = d_in[8];
    const void* fcp_w   = d_in[9];
    const void* lnf_w   = d_in[10];
    float* out = (float*)d_out;   // fp32: logits [8192,99] then loss [1]

    // workspace layout (float-slot offsets), total ~96.5 MiB
    float* ws   = (float*)d_ws;
    float* ACC  = ws;
    int*   FLAG = (int*)(ws + 4);
    bf16*  Hb   = (bf16*)(ws + 16);                      // [8192,512]  bf16 (8MB)
    float* X    = ws + 2097168;                          // [8192,512]  fp32 (16MB)
    bf16*  BIG  = (bf16*)(ws + 6291472);                 // [8192,2048] bf16 (32MB)
    bf16*  WB   = (bf16*)(ws + 14680080);                // converted weights (37.7MB)

    const int ATT_S = 3*DD*DD;        // 786432
    const int PRJ_S = DD*DD;          // 262144
    const int FC_S  = 4*DD*DD;        // 1048576
    bf16* WB_att = WB;
    bf16* WB_prj = WB + (size_t)6*ATT_S;
    bf16* WB_fc  = WB_prj + (size_t)6*PRJ_S;
    bf16* WB_fcp = WB_fc  + (size_t)6*FC_S;

    init_kernel<<<1,1,0,stream>>>((const unsigned int*)ln1_w, ACC, FLAG);
    wconv_kernel<<<(6*ATT_S)/2048,256,0,stream>>>(attn_w, WB_att, 6*ATT_S, FLAG);
    wconv_kernel<<<(6*PRJ_S)/2048,256,0,stream>>>(proj_w, WB_prj, 6*PRJ_S, FLAG);
    wconv_kernel<<<(6*FC_S)/2048,256,0,stream>>>(fc_w,  WB_fc,  6*FC_S, FLAG);
    wconv_kernel<<<(6*FC_S)/2048,256,0,stream>>>(fcp_w, WB_fcp, 6*FC_S, FLAG);
    embed_kernel<<<ROWS,256,0,stream>>>(idx, wte, wpe, X, FLAG);
    for (int l=0; l<LL; ++l){
        ln_kernel<<<ROWS,64,0,stream>>>(X, ln1_w, (size_t)l*DD, Hb, FLAG);
        gemm_mfma<0><<<dim3(3*DD/128, ROWS/128),256,0,stream>>>(Hb, WB_att + (size_t)l*ATT_S,
                                                                nullptr, BIG, ROWS, 3*DD, DD);
        attn_mfma13<<<dim3(BB*HH*16),512,0,stream>>>(BIG, Hb);
        gemm_mfma64<<<dim3(DD/128, ROWS/64),256,0,stream>>>(Hb, WB_prj + (size_t)l*PRJ_S,
                                                            X, ROWS, DD, DD);
        ln_kernel<<<ROWS,64,0,stream>>>(X, ln2_w, (size_t)l*DD, Hb, FLAG);
        gemm_mfma<2><<<dim3(4*DD/128, ROWS/128),256,0,stream>>>(Hb, WB_fc + (size_t)l*FC_S,
                                                                nullptr, BIG, ROWS, 4*DD, DD);
        gemm_mfma64<<<dim3(DD/128, ROWS/64),256,0,stream>>>(BIG, WB_fcp + (size_t)l*FC_S,
                                                            X, ROWS, DD, 4*DD);
    }
    ln_kernel<<<ROWS,64,0,stream>>>(X, lnf_w, 0, Hb, FLAG);
    gemm_nt3<<<dim3((VV+63)/64, ROWS/64),256,0,stream>>>(Hb, wte, 0, out, ROWS, VV, DD, FLAG);
    loss_kernel<<<ROWS,64,0,stream>>>(out, targets, ACC);
    fin_loss<<<1,1,0,stream>>>(ACC, out + (size_t)ROWS*VV);
}